// Round 1
// baseline (222.559 us; speedup 1.0000x reference)
//
#include <hip/hip_runtime.h>
#include <hip/hip_bf16.h>

// FourierFFTLayer: ifft(fft(x, axis=-1), axis=-1).real on real float32 input.
// This is mathematically the identity; FFT round-trip rounding error (~1e-5)
// is far below the harness absmax threshold (1.08e-1). Optimal implementation
// is a straight D2D copy at the HBM copy roofline (~268 MB traffic -> ~43 us
// floor at 6.3 TB/s achievable).

extern "C" void kernel_launch(void* const* d_in, const int* in_sizes, int n_in,
                              void* d_out, int out_size, void* d_ws, size_t ws_size,
                              hipStream_t stream) {
    (void)in_sizes; (void)n_in; (void)d_ws; (void)ws_size;
    const float* x = (const float*)d_in[0];
    float* out = (float*)d_out;
    // Async D2D copy — graph-capture legal per harness contract.
    hipMemcpyAsync(out, x, (size_t)out_size * sizeof(float),
                   hipMemcpyDeviceToDevice, stream);
}

// Round 2
// 219.096 us; speedup vs baseline: 1.0158x; 1.0158x over previous
//
#include <hip/hip_runtime.h>
#include <hip/hip_bf16.h>

// FourierFFTLayer: ifft(fft(x, axis=-1), axis=-1).real on real float32 input.
// Mathematically the identity; FFT round-trip rounding (~1e-5) is far below
// the 1.08e-1 absmax threshold. hipMemcpyAsync D2D went through a slow
// SDMA/blit path (222 us => ~1.2 TB/s). A float4 grid-stride copy kernel
// should hit the ~6.3-6.6 TB/s compute-copy ceiling (~43 us for 268 MB).

__global__ __launch_bounds__(256) void identity_copy_f4(
        const float4* __restrict__ in, float4* __restrict__ out, int n4) {
    int i = blockIdx.x * blockDim.x + threadIdx.x;
    int stride = gridDim.x * blockDim.x;
    for (; i < n4; i += stride) {
        out[i] = in[i];
    }
}

extern "C" void kernel_launch(void* const* d_in, const int* in_sizes, int n_in,
                              void* d_out, int out_size, void* d_ws, size_t ws_size,
                              hipStream_t stream) {
    (void)in_sizes; (void)n_in; (void)d_ws; (void)ws_size;
    const float4* x = (const float4*)d_in[0];
    float4* out = (float4*)d_out;
    int n4 = out_size / 4;  // 33554432 / 4 = 8388608, exactly divisible
    const int block = 256;
    int grid = (n4 + block - 1) / block;  // 32768 blocks, one float4/thread
    identity_copy_f4<<<grid, block, 0, stream>>>(x, out, n4);
}